// Round 20
// baseline (14.930 us; speedup 1.0000x reference)
//
#include <hip/hip_runtime.h>

// MosaicSDF: N=1024 points, G=512 grids, K=7 (343 nodes/grid).
// R20 = R18 with ONE point per block (straggler granularity fix).
// R18 ran 512 blocks all-resident; kernel time = slowest block (pooled
// CT tail ~250 pairs = ~8 serial chunk-rounds). R20: 1024 blocks x 512
// thr = 8192 waves = exact 32-wave/CU capacity, one point each ->
// straggler = ceil(Cmax/32) ~ 5 rounds, and phase 1 is a single ballot
// round (wave w sweeps grids [64w,64w+64)).
//   Phase 2 (R18 verbatim): 32 16-lane groups drain the point's actives
//   directly from L2 (scalar row reads -- R19 showed wide loads are
//   parity); lane owns (i,j)-rows {sub,sub+16,sub+32} (7 nodes each,
//   mul-shift div-7 decode) + row-48 tail; static dz2 table; 4-step
//   group reduce. No atomics, no workspace, one dispatch, ~9.3KB LDS.

#define NPTS   1024
#define NGRIDS 512
#define TPB    512
#define NBLK   1024            // 1 point per block
#define STEP   (1.0f / 6.0f)
#define FSQRT(x) __builtin_amdgcn_sqrtf(x)

__global__ __launch_bounds__(TPB, 4) void msdf_fused(
    const float* __restrict__ points,    // (N,3)
    const float* __restrict__ centers,   // (G,3)
    const float* __restrict__ scales,    // (G,)
    const float* __restrict__ vals,      // (G,343)
    float* __restrict__ out)             // (N,)
{
    __shared__ float4 s_pair[8][64];          // 8,192 B (rx,ry,rz,gwr)
    __shared__ unsigned short s_gid[8][64];   // 1,024 B
    __shared__ int   s_c[8];
    __shared__ float s_d[8];
    __shared__ float s_red[8];

    const int bid  = blockIdx.x;         // point id
    const int t    = threadIdx.x;
    const int w    = t >> 6;             // wave 0..7
    const int lane = t & 63;
    const int grp  = t >> 4;             // 0..31: 16-lane group (pair slot)
    const int sub  = t & 15;

    const float px = points[bid * 3 + 0];    // block-uniform -> scalar loads
    const float py = points[bid * 3 + 1];
    const float pz = points[bid * 3 + 2];

    // ---- Phase 1: single ballot round (wave w owns grids 64w..64w+63) ----
    {
        const int g = (w << 6) + lane;
        const float invs = 1.0f / scales[g];
        const float rx = (px - centers[g * 3 + 0]) * invs;
        const float ry = (py - centers[g * 3 + 1]) * invs;
        const float rz = (pz - centers[g * 3 + 2]) * invs;
        const float gwr = 1.0f - FSQRT(rx * rx + ry * ry + rz * rz);
        const bool  act = (gwr > 0.0f);
        const unsigned long long m = __ballot(act);
        if (act) {
            const int pos = (int)__popcll(m & ((1ull << lane) - 1ull));
            s_pair[w][pos] = make_float4(rx, ry, rz, gwr);
            s_gid[w][pos]  = (unsigned short)g;
        }
        float dsum = act ? gwr : 0.0f;
        #pragma unroll
        for (int o = 32; o >= 1; o >>= 1) dsum += __shfl_xor(dsum, o);
        if (lane == 0) { s_c[w] = (int)__popcll(m); s_d[w] = dsum; }
    }
    __syncthreads();

    const int o1 = s_c[0];
    const int o2 = o1 + s_c[1];
    const int o3 = o2 + s_c[2];
    const int o4 = o3 + s_c[3];
    const int o5 = o4 + s_c[4];
    const int o6 = o5 + s_c[5];
    const int o7 = o6 + s_c[6];
    const int C  = o7 + s_c[7];
    const float den = s_d[0] + s_d[1] + s_d[2] + s_d[3]
                    + s_d[4] + s_d[5] + s_d[6] + s_d[7];

    // ---- Phase 2: 32 16-lane groups, direct-from-L2 rows ----
    float acc = 0.0f;
    for (int a = grp; a < C; a += 32) {
        const int seg = (a >= o1) + (a >= o2) + (a >= o3) + (a >= o4)
                      + (a >= o5) + (a >= o6) + (a >= o7);
        const int b0  = (seg == 0) ? 0 : (seg == 1) ? o1
                      : (seg == 2) ? o2 : (seg == 3) ? o3
                      : (seg == 4) ? o4 : (seg == 5) ? o5
                      : (seg == 6) ? o6 : o7;
        const float4 pr  = s_pair[seg][a - b0];
        const int    gid = (int)s_gid[seg][a - b0];
        const float* __restrict__ grow = vals + gid * 343;

        float dz2[7];                                // static-indexed -> regs
        #pragma unroll
        for (int l = 0; l < 7; ++l) { const float d = pr.z - l * STEP; dz2[l] = d * d; }

        float ws = 0.0f, vs = 0.0f;
        #pragma unroll
        for (int rr = 0; rr < 3; ++rr) {
            const int rowid = sub + (rr << 4);       // 0..47
            const int i = (rowid * 9363) >> 16;      // rowid / 7
            const int j = rowid - i * 7;
            const float dxv = pr.x - (float)i * STEP;
            const float dyv = pr.y - (float)j * STEP;
            const float dxy = dxv * dxv + dyv * dyv;
            const float* __restrict__ vr = grow + rowid * 7;   // L1/L2-hit
            #pragma unroll
            for (int l = 0; l < 7; ++l) {
                const float d2 = dxy + dz2[l];
                const float wt = (d2 <= 1.0f) ? FSQRT(d2) : 0.0f;
                ws += wt;
                vs  = fmaf(wt, vr[l], vs);
            }
        }
        if (sub < 7) {                               // row 48: node (6,6,sub)
            const float dxv = pr.x - 1.0f;
            const float dyv = pr.y - 1.0f;
            const float dzv = pr.z - (float)sub * STEP;
            const float d2  = dxv * dxv + dyv * dyv + dzv * dzv;
            const float wt  = (d2 <= 1.0f) ? FSQRT(d2) : 0.0f;
            ws += wt;
            vs  = fmaf(wt, grow[336 + sub], vs);
        }
        #pragma unroll
        for (int o = 8; o >= 1; o >>= 1) {
            ws += __shfl_xor(ws, o);
            vs += __shfl_xor(vs, o);
        }
        const float interp = (ws > 0.0f) ? (vs / ws) : 0.0f;
        if (sub == 0) acc += interp * pr.w;
    }

    // Block reduction: butterfly per wave, then cross-wave via LDS.
    #pragma unroll
    for (int o = 32; o >= 1; o >>= 1) acc += __shfl_xor(acc, o);
    if (lane == 0) s_red[w] = acc;
    __syncthreads();
    if (t == 0) {
        const float nm = s_red[0] + s_red[1] + s_red[2] + s_red[3]
                       + s_red[4] + s_red[5] + s_red[6] + s_red[7];
        out[bid] = (den > 0.0f) ? (nm / den) : 0.0f;
    }
}

extern "C" void kernel_launch(void* const* d_in, const int* in_sizes, int n_in,
                              void* d_out, int out_size, void* d_ws, size_t ws_size,
                              hipStream_t stream) {
    const float* points  = (const float*)d_in[0];   // (1024,3)
    const float* centers = (const float*)d_in[1];   // (512,3)
    const float* scales  = (const float*)d_in[2];   // (512,)
    const float* vals    = (const float*)d_in[3];   // (512,7,7,7)
    float* out = (float*)d_out;                     // (1024,)

    msdf_fused<<<NBLK, TPB, 0, stream>>>(points, centers, scales, vals, out);
}